// Round 3
// baseline (621.386 us; speedup 1.0000x reference)
//
#include <hip/hip_runtime.h>

#define M_TOTAL   2000000
#define NT        512
#define K1_BLOCKS 2048

__device__ __forceinline__ float rlf(float v, int l) {
    union { float f; int i; } u; u.f = v;
    u.i = __builtin_amdgcn_readlane(u.i, l);
    return u.f;
}

// Barrier with LDS-only drain: in-loop cross-thread data is exclusively LDS,
// so vmcnt (global outL stores / gum / Rtab loads) never needs draining.
__device__ __forceinline__ void bar_lds() {
    asm volatile("s_waitcnt lgkmcnt(0)" ::: "memory");
    __builtin_amdgcn_s_barrier();
    asm volatile("" ::: "memory");
}

#define REP16(M)  M(0) M(1) M(2) M(3) M(4) M(5) M(6) M(7) M(8) M(9) M(10) M(11) M(12) M(13) M(14) M(15)
#define REP8(M)   M(0) M(1) M(2) M(3) M(4) M(5) M(6) M(7)

// Volatile load of 4 consecutive floats: performed exactly once, where written;
// the compiler cannot sink/rematerialize these inside the step loop.
#define VLD4(dst, base, c) { const volatile float* _p = (base) + 4*(c); \
    dst.x = _p[0]; dst.y = _p[1]; dst.z = _p[2]; dst.w = _p[3]; }

// -------------------- K1: partial sums of v_src@embs and v_target@embs (coalesced) --------------------
extern "C" __global__ __launch_bounds__(256)
void k_reduce(const float* __restrict__ emb, const float* __restrict__ vsrc,
              const float* __restrict__ vtgt, double* __restrict__ partials)
{
    const int tid = threadIdx.x;
    const int bid = blockIdx.x;
    double aS[4], aT[4];
#pragma unroll
    for (int i = 0; i < 4; i++) { aS[i] = 0.0; aT[i] = 0.0; }

    const float4* emb4 = (const float4*)emb;
    for (long long f = (long long)bid * 256 + tid; f < (long long)M_TOTAL * 4;
         f += (long long)K1_BLOCKS * 256) {
        float4 e = emb4[f];
        long long r = f >> 2;
        float sq = fmaf(e.x, e.x, fmaf(e.y, e.y, fmaf(e.z, e.z, e.w * e.w)));
        sq += __shfl_xor(sq, 1);
        sq += __shfl_xor(sq, 2);
        float invn = 1.0f / sqrtf(sq);
        float s = vsrc[r] * invn;
        float t = vtgt[r] * invn;
        aS[0] += (double)(s * e.x); aS[1] += (double)(s * e.y);
        aS[2] += (double)(s * e.z); aS[3] += (double)(s * e.w);
        aT[0] += (double)(t * e.x); aT[1] += (double)(t * e.y);
        aT[2] += (double)(t * e.z); aT[3] += (double)(t * e.w);
    }
#pragma unroll
    for (int i = 0; i < 4; i++) {
#pragma unroll
        for (int off = 32; off >= 4; off >>= 1) {
            aS[i] += __shfl_down(aS[i], off);
            aT[i] += __shfl_down(aT[i], off);
        }
    }
    __shared__ double lred[4][32];
    int lane = tid & 63, wv = tid >> 6;
    if (lane < 4) {
#pragma unroll
        for (int i = 0; i < 4; i++) {
            lred[wv][lane * 4 + i]      = aS[i];
            lred[wv][16 + lane * 4 + i] = aT[i];
        }
    }
    __syncthreads();
    if (tid < 32) {
        double v = lred[0][tid] + lred[1][tid] + lred[2][tid] + lred[3][tid];
        partials[(long long)bid * 32 + tid] = v;
    }
}

// -------------------- K_expm: Rtab[t] = expm(gens[t]) for all 512 transitions --------------------
extern "C" __global__ __launch_bounds__(256)
void k_expm(const float* __restrict__ tc, float* __restrict__ Rtab)
{
    const int b = blockIdx.x;      // transition index
    const int t = threadIdx.x;     // element (i,j)
    const int i = t >> 4, j = t & 15;
    __shared__ float Om[256];
    __shared__ float Ms[256];

    const float* crow = tc + b * 120;
    float o = 0.0f;
    if (i < j)      o = -crow[(i * (31 - i)) / 2 + (j - i - 1)];
    else if (i > j) o =  crow[(j * (31 - j)) / 2 + (i - j - 1)];
    Om[t] = o;
    Ms[t] = o;
    float s = (i == j ? 1.0f : 0.0f) + o;   // S = I + Omega
    __syncthreads();

#pragma unroll
    for (int k = 2; k <= 16; k++) {
        float a0 = 0.0f, a1 = 0.0f, a2 = 0.0f, a3 = 0.0f;
#pragma unroll
        for (int m = 0; m < 4; m++) {
            a0 = fmaf(Om[i * 16 + m],      Ms[m * 16 + j],        a0);
            a1 = fmaf(Om[i * 16 + 4 + m],  Ms[(4 + m) * 16 + j],  a1);
            a2 = fmaf(Om[i * 16 + 8 + m],  Ms[(8 + m) * 16 + j],  a2);
            a3 = fmaf(Om[i * 16 + 12 + m], Ms[(12 + m) * 16 + j], a3);
        }
        float acc = ((a0 + a1) + (a2 + a3)) * (1.0f / (float)k);
        __syncthreads();
        Ms[t] = acc;
        s += acc;
        __syncthreads();
    }
    Rtab[b * 256 + t] = s;
}

// -------------------- K_prep: per-thread-contiguous weight layouts for 1024-thread k_steps --------------------
// k_steps thread t: L3 owns (o = t&511, hh = t>>9), needs w3[hh*64+m][o], m=0..63.
//                   L2 owns (j = t&127, p = t>>7), needs w2[p*32+m][j],  m=0..31.
extern "C" __global__ __launch_bounds__(64)
void k_prep(const float* __restrict__ w2g, const float* __restrict__ w3g,
            float* __restrict__ w2R, float* __restrict__ w3R)
{
    const int b = blockIdx.x;    // 0..1023 = k_steps thread id
    const int l = threadIdx.x;   // 0..63
    const int o = b & 511, hh = b >> 9;
    w3R[b * 64 + l] = w3g[(hh * 64 + l) * 512 + o];
    if (l < 32) {
        const int p = b >> 7, j = b & 127;
        w2R[b * 32 + l] = w2g[(p * 32 + l) * 128 + j];
    }
}

// -------------------- K2: the sequential 64-step scan (1 block, 1024 threads = 16 waves) --------------------
// 4 waves/SIMD for latency hiding; per-thread weight footprint 96 floats (w3 64 + w2 32)
// so the 128-VGPR budget holds everything with NO spilling.
extern "C" __global__ __launch_bounds__(1024)
__attribute__((amdgpu_waves_per_eu(4, 4)))
void k_steps(const double* __restrict__ partials,
             const float* __restrict__ w1g, const float* __restrict__ b1g,
             const float* __restrict__ b2g, const float* __restrict__ b3g,
             const float* __restrict__ w2R, const float* __restrict__ w3R,
             const float* __restrict__ Rtab, const float* __restrict__ gum,
             const int* __restrict__ nsp,
             float* __restrict__ outL, float* __restrict__ vf_out)
{
    __shared__ float w1s[16 * 256];   // v-half of w1 only (v_tgt half folded into b1e)
    __shared__ float h1s[256];
    __shared__ float h2p[1024];       // L2 partials, 8-way K split (32 K-elems each)
    __shared__ float lgp[1024];       // L3 partials, 2-way K split (64 K-elems each)
    __shared__ float xs[32];
    __shared__ float b2s[128];
    __shared__ float rkeys[8];
    __shared__ int   ridx[8];

    const int t = threadIdx.x;
    const int lane = t & 63;
    const int wv = t >> 6;

    // ---- register-resident weights via volatile one-time loads ----
    const volatile float* w3v = (const volatile float*)(w3R + (size_t)t * 64);
    const volatile float* w2v = (const volatile float*)(w2R + (size_t)t * 32);
#define W3D(c) float4 w3_##c; VLD4(w3_##c, w3v, c)
    REP16(W3D)
#undef W3D
#define W2D(c) float4 w2_##c; VLD4(w2_##c, w2v, c)
    REP8(W2D)
#undef W2D
    const float b3r = (t < 512) ? b3g[t] : 0.0f;

    // stage w1 v-half rows + b2 into LDS
    for (int i = t; i < 16 * 256; i += 1024) w1s[i] = w1g[i];
    if (t < 128) b2s[t] = b2g[t];

    // warm Rtab (512 KB) into this XCD's L2 so per-step rotation loads hit L2 not HBM
    float warm = 0.0f;
    for (int i = t; i < 512 * 256 / 4; i += 1024) {
        float4 rv = ((const float4*)Rtab)[i];
        warm += (rv.x + rv.y) + (rv.z + rv.w);
    }

    // stage-2 reduce of K1 partials -> xs[0:16]=v_cur, xs[16:32]=v_tgt
    {
        int c = t >> 5, r = t & 31;
        double v = 0.0;
        for (int k = r; k < K1_BLOCKS; k += 32) v += partials[k * 32 + c];
        v += __shfl_xor(v, 1); v += __shfl_xor(v, 2);
        v += __shfl_xor(v, 4); v += __shfl_xor(v, 8);
        v += __shfl_xor(v, 16);
        if (r == 0) xs[c] = (float)v;
    }

    int ns = nsp[0];
    if (ns > 64) ns = 64;
    if (ns < 0)  ns = 0;
    if (ns == -2147483647) vf_out[0] = warm;   // never true; defeats DCE

    __syncthreads();

    // b1_eff = b1 + v_tgt @ w1[16:32]; v replicated per-wave (waves 0-3 only)
    float b1e = 0.0f, vreg = 0.0f;
    if (t < 256) {
        float a = b1g[t];
#pragma unroll
        for (int m = 0; m < 16; m++)
            a = fmaf(xs[16 + m], w1g[(16 + m) * 256 + t], a);
        b1e = a;
        vreg = xs[lane & 15];        // lane l holds v[l&15]
    }

    if (ns == 0 && t < 16) vf_out[t] = xs[t];

    const int i16 = lane & 15, q4 = lane >> 4;  // rotation lane mapping (per wave)

    for (int step = 0; step < ns; step++) {
        float gv = (t < 512) ? gum[step * 512 + t] : 0.0f;

        // ---- layer 1: h1 = relu(v @ w1[0:16] + b1_eff); waves 0-3, v in own-wave regs ----
        if (t < 256) {
            float a0 = 0.0f, a1 = 0.0f;
#pragma unroll
            for (int m = 0; m < 8; m++) {
                a0 = fmaf(rlf(vreg, m),     w1s[m * 256 + t],       a0);
                a1 = fmaf(rlf(vreg, 8 + m), w1s[(8 + m) * 256 + t], a1);
            }
            h1s[t] = fmaxf((a0 + a1) + b1e, 0.0f);
        }
        bar_lds();

        // ---- layer 2 partials: 128 outputs x 8-way K split (32 each), all 16 waves ----
        {
            float h1seg = h1s[((t >> 7) << 5) | (lane & 31)];   // h1[p*32 + (lane&31)]
            float a0 = 0.0f, a1 = 0.0f, a2 = 0.0f, a3 = 0.0f;
#define L2C(c) { a0 = fmaf(rlf(h1seg, 4*(c)+0), w2_##c.x, a0); \
                 a1 = fmaf(rlf(h1seg, 4*(c)+1), w2_##c.y, a1); \
                 a2 = fmaf(rlf(h1seg, 4*(c)+2), w2_##c.z, a2); \
                 a3 = fmaf(rlf(h1seg, 4*(c)+3), w2_##c.w, a3); }
            REP8(L2C)
#undef L2C
            h2p[t] = (a0 + a1) + (a2 + a3);
        }
        bar_lds();

        // ---- layer 3 partials: fused h2 reconstruct + 64-K dot, all 16 waves ----
        {
            const int hbl = ((t >> 9) << 6) + lane;   // hh*64 + lane
            float s = b2s[hbl];
#pragma unroll
            for (int p = 0; p < 8; p++) s += h2p[p * 128 + hbl];
            float h2seg = fmaxf(s, 0.0f);             // lane l holds h2[hh*64 + l]
            float lg0 = 0.0f, lg1 = 0.0f, lg2 = 0.0f, lg3 = 0.0f;
#define L3C(c) { lg0 = fmaf(rlf(h2seg, 4*(c)+0), w3_##c.x, lg0); \
                 lg1 = fmaf(rlf(h2seg, 4*(c)+1), w3_##c.y, lg1); \
                 lg2 = fmaf(rlf(h2seg, 4*(c)+2), w3_##c.z, lg2); \
                 lg3 = fmaf(rlf(h2seg, 4*(c)+3), w3_##c.w, lg3); }
            REP16(L3C)
#undef L3C
            lgp[t] = (lg0 + lg1) + (lg2 + lg3);
        }
        bar_lds();

        // ---- final logits + argmax(logits + gumbel), waves 0-7 ----
        if (t < 512) {
            float lg = (lgp[t] + lgp[512 + t]) + b3r;
            outL[step * 512 + t] = lg;     // fire-and-forget; lgkm barriers don't drain vmcnt
            float key = lg + gv;
            int   idx = t;
#pragma unroll
            for (int off = 32; off; off >>= 1) {
                float ok = __shfl_down(key, off);
                int   oi = __shfl_down(idx, off);
                if (ok > key || (ok == key && oi < idx)) { key = ok; idx = oi; }
            }
            if (lane == 0) { rkeys[wv] = key; ridx[wv] = idx; }
        }
        bar_lds();

        // ---- rotation: waves 0-3 redundantly compute v = normalize(R[bi] @ v) ----
        if (t < 256) {
            float bk = rkeys[0]; int bi = ridx[0];
#pragma unroll
            for (int w = 1; w < 8; w++) {
                float ok = rkeys[w]; int oi = ridx[w];
                if (ok > bk || (ok == bk && oi < bi)) { bk = ok; bi = oi; }
            }
            const float4 rr = *(const float4*)(Rtab + bi * 256 + i16 * 16 + 4 * q4);
            float rw0 = __shfl(vreg, 20 * q4 + 0);
            float rw1 = __shfl(vreg, 20 * q4 + 1);
            float rw2 = __shfl(vreg, 20 * q4 + 2);
            float rw3 = __shfl(vreg, 20 * q4 + 3);
            float pr = rr.x * rw0;
            pr = fmaf(rr.y, rw1, pr);
            pr = fmaf(rr.z, rw2, pr);
            pr = fmaf(rr.w, rw3, pr);
            pr += __shfl_xor(pr, 16);
            pr += __shfl_xor(pr, 32);
            float n2 = pr * pr;
            n2 += __shfl_xor(n2, 1);
            n2 += __shfl_xor(n2, 2);
            n2 += __shfl_xor(n2, 4);
            n2 += __shfl_xor(n2, 8);
            float invn = 1.0f / sqrtf(n2);
            vreg = pr * invn;                  // lane l holds v'[l&15], waves 0-3 consistent
            if (step == ns - 1 && t < 16) vf_out[t] = vreg;
        }
        // no barrier here: next L1 uses only own-wave registers; h1s writes are
        // separated from this step's readers by the barriers above.
    }
}

// -------------------- K3: scores = exp(dot(v_fin, emb_row_norm)), coalesced --------------------
extern "C" __global__ __launch_bounds__(256)
void k_scores(const float* __restrict__ emb, const float* __restrict__ vf16,
              float* __restrict__ outP, double* __restrict__ sums)
{
    __shared__ float vfs[16];
    const int tid = threadIdx.x;
    const int bid = blockIdx.x;
    const int q = tid & 3;
    if (tid < 16) vfs[tid] = vf16[tid];
    __syncthreads();
    float v0 = vfs[q * 4 + 0], v1 = vfs[q * 4 + 1], v2 = vfs[q * 4 + 2], v3 = vfs[q * 4 + 3];

    const float4* emb4 = (const float4*)emb;
    double bsum = 0.0;
    for (long long f = (long long)bid * 256 + tid; f < (long long)M_TOTAL * 4;
         f += (long long)K1_BLOCKS * 256) {
        float4 e = emb4[f];
        long long r = f >> 2;
        float sq = fmaf(e.x, e.x, fmaf(e.y, e.y, fmaf(e.z, e.z, e.w * e.w)));
        float d  = fmaf(e.x, v0, fmaf(e.y, v1, fmaf(e.z, v2, e.w * v3)));
        sq += __shfl_xor(sq, 1);  d += __shfl_xor(d, 1);
        sq += __shfl_xor(sq, 2);  d += __shfl_xor(d, 2);
        float ex = expf(d / sqrtf(sq));   // |score| <= 1, no overflow; softmax shift cancels
        if (q == 0) {
            outP[r] = ex;
            bsum += (double)ex;
        }
    }
#pragma unroll
    for (int off = 4; off <= 32; off <<= 1) bsum += __shfl_down(bsum, off);
    __shared__ double lred[4];
    if ((tid & 63) == 0) lred[tid >> 6] = bsum;
    __syncthreads();
    if (tid == 0) sums[bid] = lred[0] + lred[1] + lred[2] + lred[3];
}

// -------------------- K4: total and reciprocal --------------------
extern "C" __global__ __launch_bounds__(256)
void k_total(const double* __restrict__ sums, double* __restrict__ invp)
{
    const int tid = threadIdx.x;
    double v = 0.0;
    for (int k = tid; k < K1_BLOCKS; k += 256) v += sums[k];
#pragma unroll
    for (int off = 32; off; off >>= 1) v += __shfl_down(v, off);
    __shared__ double lred[4];
    if ((tid & 63) == 0) lred[tid >> 6] = v;
    __syncthreads();
    if (tid == 0) invp[0] = 1.0 / (lred[0] + lred[1] + lred[2] + lred[3]);
}

// -------------------- K5: normalize --------------------
extern "C" __global__ __launch_bounds__(256)
void k_scale(float* __restrict__ outP, const double* __restrict__ invp)
{
    const float inv = (float)invp[0];
    long long r4 = (long long)blockIdx.x * 256 + threadIdx.x;
    if (r4 < M_TOTAL / 4) {
        float4* p = (float4*)outP;
        float4 v = p[r4];
        v.x *= inv; v.y *= inv; v.z *= inv; v.w *= inv;
        p[r4] = v;
    }
}

extern "C" void kernel_launch(void* const* d_in, const int* in_sizes, int n_in,
                              void* d_out, int out_size, void* d_ws, size_t ws_size,
                              hipStream_t stream)
{
    const float* vsrc = (const float*)d_in[0];
    const float* vtgt = (const float*)d_in[1];
    const float* emb  = (const float*)d_in[2];
    const float* tc   = (const float*)d_in[3];
    // d_in[4] = bases: structure is hard-coded (omega[i][j] = -/+ coeffs[t*, k(i,j)])
    const float* w1 = (const float*)d_in[5];
    const float* b1 = (const float*)d_in[6];
    const float* w2 = (const float*)d_in[7];
    const float* b2 = (const float*)d_in[8];
    const float* w3 = (const float*)d_in[9];
    const float* b3 = (const float*)d_in[10];
    const float* gum = (const float*)d_in[11];
    const int* nsp   = (const int*)d_in[12];

    float* outP = (float*)d_out;          // pred_marking [2M]
    float* outL = outP + M_TOTAL;         // logits [64*512]

    double* wsd      = (double*)d_ws;
    double* partials = wsd;                         // 2048*32 doubles
    double* sums     = wsd + K1_BLOCKS * 32;        // 2048 doubles
    double* invp     = sums + K1_BLOCKS;            // 1 double
    float*  vf       = (float*)(invp + 1);          // 16 floats

    // Scratch tables live in the pred_marking output region; fully consumed by
    // k_steps before k_scores/k_scale overwrite outP.
    float* Rtab = outP;                   // 512*256 = 131072 floats
    float* w3R  = outP + 131072;          // 1024*64 =  65536 floats
    float* w2R  = outP + 196608;          // 1024*32 =  32768 floats

    k_expm<<<NT, 256, 0, stream>>>(tc, Rtab);
    k_prep<<<1024, 64, 0, stream>>>(w2, w3, w2R, w3R);
    k_reduce<<<K1_BLOCKS, 256, 0, stream>>>(emb, vsrc, vtgt, partials);
    k_steps<<<1, 1024, 0, stream>>>(partials, w1, b1, b2, b3, w2R, w3R, Rtab, gum, nsp, outL, vf);
    k_scores<<<K1_BLOCKS, 256, 0, stream>>>(emb, vf, outP, sums);
    k_total<<<1, 256, 0, stream>>>(sums, invp);
    k_scale<<<(M_TOTAL / 4 + 255) / 256, 256, 0, stream>>>(outP, invp);
}

// Round 4
// 469.446 us; speedup vs baseline: 1.3237x; 1.3237x over previous
//
#include <hip/hip_runtime.h>

#define M_TOTAL   2000000
#define NT        512
#define K1_BLOCKS 1024
#define K3_BLOCKS 2048

__device__ __forceinline__ float rlf(float v, int l) {
    union { float f; int i; } u; u.f = v;
    u.i = __builtin_amdgcn_readlane(u.i, l);
    return u.f;
}

// Barrier with LDS-only drain: in-loop cross-thread data is exclusively LDS,
// so vmcnt (global outL stores / gum / Rtab loads) never needs draining.
__device__ __forceinline__ void bar_lds() {
    asm volatile("s_waitcnt lgkmcnt(0)" ::: "memory");
    __builtin_amdgcn_s_barrier();
    asm volatile("" ::: "memory");
}

// DPP helpers (register-crossbar cross-lane, ~4cy vs ~100cy for ds_bpermute shuffles).
// bound_ctrl=true -> out-of-range source lanes read 0 (identity for u32-max and f32-add here).
#define DPPMAXU(m, ctrl) { unsigned _d = (unsigned)__builtin_amdgcn_update_dpp(0, (int)(m), (ctrl), 0xF, 0xF, true); \
                           if (_d > (m)) (m) = _d; }
#define DPPADDF(s, ctrl) { float _d = __int_as_float(__builtin_amdgcn_update_dpp(0, __float_as_int(s), (ctrl), 0xF, 0xF, true)); \
                           (s) += _d; }

__device__ __forceinline__ unsigned orderf(float f) {
    unsigned u = __float_as_uint(f);
    return u ^ (((unsigned)((int)u >> 31)) | 0x80000000u);   // monotone float->uint
}

__device__ __forceinline__ uint2 pick2(uint2 a, uint2 b) {
    // larger key wins; equal key -> smaller index (first-index tiebreak)
    bool takeb = (b.x > a.x) || (b.x == a.x && b.y < a.y);
    return takeb ? b : a;
}

#define REP16(M)  M(0) M(1) M(2) M(3) M(4) M(5) M(6) M(7) M(8) M(9) M(10) M(11) M(12) M(13) M(14) M(15)
#define REP16B(M) M(16) M(17) M(18) M(19) M(20) M(21) M(22) M(23) M(24) M(25) M(26) M(27) M(28) M(29) M(30) M(31)

// Volatile load of 4 consecutive floats: performed exactly once, where written;
// the compiler cannot sink/rematerialize these inside the step loop.
#define VLD4(dst, base, c) { const volatile float* _p = (base) + 4*(c); \
    dst.x = _p[0]; dst.y = _p[1]; dst.z = _p[2]; dst.w = _p[3]; }

// -------------------- K1: partial sums of v_src@embs and v_target@embs (coalesced) --------------------
extern "C" __global__ __launch_bounds__(256)
void k_reduce(const float* __restrict__ emb, const float* __restrict__ vsrc,
              const float* __restrict__ vtgt, double* __restrict__ partials)
{
    const int tid = threadIdx.x;
    const int bid = blockIdx.x;
    double aS[4], aT[4];
#pragma unroll
    for (int i = 0; i < 4; i++) { aS[i] = 0.0; aT[i] = 0.0; }

    const float4* emb4 = (const float4*)emb;
    for (long long f = (long long)bid * 256 + tid; f < (long long)M_TOTAL * 4;
         f += (long long)K1_BLOCKS * 256) {
        float4 e = emb4[f];
        long long r = f >> 2;
        float sq = fmaf(e.x, e.x, fmaf(e.y, e.y, fmaf(e.z, e.z, e.w * e.w)));
        sq += __shfl_xor(sq, 1);
        sq += __shfl_xor(sq, 2);
        float invn = 1.0f / sqrtf(sq);
        float s = vsrc[r] * invn;
        float t = vtgt[r] * invn;
        aS[0] += (double)(s * e.x); aS[1] += (double)(s * e.y);
        aS[2] += (double)(s * e.z); aS[3] += (double)(s * e.w);
        aT[0] += (double)(t * e.x); aT[1] += (double)(t * e.y);
        aT[2] += (double)(t * e.z); aT[3] += (double)(t * e.w);
    }
#pragma unroll
    for (int i = 0; i < 4; i++) {
#pragma unroll
        for (int off = 32; off >= 4; off >>= 1) {
            aS[i] += __shfl_down(aS[i], off);
            aT[i] += __shfl_down(aT[i], off);
        }
    }
    __shared__ double lred[4][32];
    int lane = tid & 63, wv = tid >> 6;
    if (lane < 4) {
#pragma unroll
        for (int i = 0; i < 4; i++) {
            lred[wv][lane * 4 + i]      = aS[i];
            lred[wv][16 + lane * 4 + i] = aT[i];
        }
    }
    __syncthreads();
    if (tid < 32) {
        double v = lred[0][tid] + lred[1][tid] + lred[2][tid] + lred[3][tid];
        partials[(long long)bid * 32 + tid] = v;
    }
}

// -------------------- K_pre: fused expm (blocks 0..511) + weight re-layout (512..1027) + total zero --------------------
extern "C" __global__ __launch_bounds__(256)
void k_pre(const float* __restrict__ tc, float* __restrict__ Rtab,
           const float* __restrict__ w2g, const float* __restrict__ w3g,
           float* __restrict__ w2R, float* __restrict__ w3R,
           double* __restrict__ totalp)
{
    const int bid = blockIdx.x;
    const int t = threadIdx.x;

    if (bid < 512) {
        // ---- expm(gens[bid]) via 16-term Taylor on the 16x16 skew matrix ----
        const int i = t >> 4, j = t & 15;
        __shared__ float Om[256];
        __shared__ float Ms[256];

        const float* crow = tc + bid * 120;
        float o = 0.0f;
        if (i < j)      o = -crow[(i * (31 - i)) / 2 + (j - i - 1)];
        else if (i > j) o =  crow[(j * (31 - j)) / 2 + (i - j - 1)];
        Om[t] = o;
        Ms[t] = o;
        float s = (i == j ? 1.0f : 0.0f) + o;   // S = I + Omega
        __syncthreads();

#pragma unroll
        for (int k = 2; k <= 16; k++) {
            float a0 = 0.0f, a1 = 0.0f, a2 = 0.0f, a3 = 0.0f;
#pragma unroll
            for (int m = 0; m < 4; m++) {
                a0 = fmaf(Om[i * 16 + m],      Ms[m * 16 + j],        a0);
                a1 = fmaf(Om[i * 16 + 4 + m],  Ms[(4 + m) * 16 + j],  a1);
                a2 = fmaf(Om[i * 16 + 8 + m],  Ms[(8 + m) * 16 + j],  a2);
                a3 = fmaf(Om[i * 16 + 12 + m], Ms[(12 + m) * 16 + j], a3);
            }
            float acc = ((a0 + a1) + (a2 + a3)) * (1.0f / (float)k);
            __syncthreads();
            Ms[t] = acc;
            s += acc;
            __syncthreads();
        }
        Rtab[bid * 256 + t] = s;
    } else {
        // ---- per-thread-contiguous weight layouts for 512-thread k_steps ----
        if (bid == 512 && t == 0) totalp[0] = 0.0;   // zero softmax denominator accumulator
        if (t >= 128) return;
        const int b = bid - 512;     // 0..515
        const int k = t;             // 0..127
        if (b < 512) {
            w3R[b * 128 + k] = w3g[k * 512 + b];
        } else {
            const int p2 = b - 512;     // 0..3
            const int j2 = k;           // 0..127
            for (int m = 0; m < 64; m++)
                w2R[(((p2 << 7) | j2) * 64) + m] = w2g[(64 * p2 + m) * 128 + j2];
        }
    }
}

// -------------------- K2: the sequential 64-step scan (1 block, 512 threads) --------------------
// R1 structure (proven 292us, VGPR=128) with every __shfl removed from the step loop:
// argmax via DPP wave-max + ballot; rotation via lanes 0-15 readlane + DPP row-sum.
extern "C" __global__ __launch_bounds__(512)
__attribute__((amdgpu_waves_per_eu(2, 2)))
void k_steps(const double* __restrict__ partials,
             const float* __restrict__ w1g, const float* __restrict__ b1g,
             const float* __restrict__ b2g, const float* __restrict__ b3g,
             const float* __restrict__ w2R, const float* __restrict__ w3R,
             const float* __restrict__ Rtab, const float* __restrict__ gum,
             const int* __restrict__ nsp,
             float* __restrict__ outL, float* __restrict__ vf_out)
{
    __shared__ float h1s[256];
    __shared__ float h2p[512];
    __shared__ float xs[32];
    __shared__ float b2s[128];
    __shared__ uint2 kidx[8];
    __shared__ double dred[512];

    const int t = threadIdx.x;
    const int lane = t & 63;
    const int wv = t >> 6;
    const int j2 = t & 127, p2 = t >> 7;
    const int c1 = t & 255;           // L1 output column (threads 256-511 shadow 0-255)

    // ---- register-resident weights via volatile one-time loads (R1 layout) ----
    const volatile float* w3v = (const volatile float*)(w3R + (size_t)t * 128);
    const volatile float* w2v = (const volatile float*)(w2R + (size_t)t * 64);
#define W3D(c) float4 w3_##c; VLD4(w3_##c, w3v, c)
    REP16(W3D) REP16B(W3D)
#undef W3D
#define W2D(c) float4 w2_##c; VLD4(w2_##c, w2v, c)
    REP16(W2D)
#undef W2D
    const float b3r = b3g[t];

    // w1 v-half columns in registers (16 floats, static indexing only)
    float w1r[16];
    {
        const volatile float* w1v = (const volatile float*)w1g;
#pragma unroll
        for (int m = 0; m < 16; m++) w1r[m] = w1v[m * 256 + c1];
    }
    if (t < 128) b2s[t] = b2g[t];

    // warm Rtab (512 KB) into this XCD's L2 so per-step rotation loads hit L2 not HBM
    float warm = 0.0f;
    for (int i = t; i < 512 * 256 / 4; i += 512) {
        float4 rv = ((const float4*)Rtab)[i];
        warm += (rv.x + rv.y) + (rv.z + rv.w);
    }

    // stage-2 reduce of K1 partials, coalesced: flat[f] has column f%32
    {
        double v = 0.0;
#pragma unroll 4
        for (int i = 0; i < (K1_BLOCKS * 32) / 512; i++) v += partials[i * 512 + t];
        dred[t] = v;
    }

    int ns = nsp[0];
    if (ns > 64) ns = 64;
    if (ns < 0)  ns = 0;
    if (ns == -2147483647) vf_out[0] = warm;   // never true; defeats DCE

    __syncthreads();
    if (t < 32) {
        double s = 0.0;
#pragma unroll
        for (int j = 0; j < 16; j++) s += dred[t + 32 * j];
        xs[t] = (float)s;                      // xs[0:16]=v_cur, xs[16:32]=v_tgt
    }
    __syncthreads();

    // b1_eff = b1 + v_tgt @ w1[16:32]; v replicated per-wave (waves 0-3 only)
    float b1e = 0.0f, vreg = 0.0f;
    if (t < 256) {
        float a = b1g[c1];
#pragma unroll
        for (int m = 0; m < 16; m++)
            a = fmaf(xs[16 + m], w1g[(16 + m) * 256 + c1], a);
        b1e = a;
        vreg = xs[lane & 15];        // lane l holds v[l&15]
    }

    if (ns == 0 && t < 16) vf_out[t] = xs[t];

    for (int step = 0; step < ns; step++) {
        float gv = gum[step * 512 + t];       // hoisted global load (needed at argmax)

        // ---- layer 1: h1 = relu(v @ w1[0:16] + b1_eff); waves 0-3, v in own-wave regs ----
        if (t < 256) {
            float a0 = 0.0f, a1 = 0.0f;
#pragma unroll
            for (int m = 0; m < 8; m++) {
                a0 = fmaf(rlf(vreg, m),     w1r[m],     a0);
                a1 = fmaf(rlf(vreg, 8 + m), w1r[8 + m], a1);
            }
            h1s[t] = fmaxf((a0 + a1) + b1e, 0.0f);
        }
        bar_lds();

        // ---- layer 2 partials: 128 outputs x 4-way K split ----
        {
            float h1seg = h1s[(p2 << 6) | lane];
            float a0 = 0.0f, a1 = 0.0f, a2 = 0.0f, a3 = 0.0f;
#define L2C(c) { a0 = fmaf(rlf(h1seg, 4*(c)+0), w2_##c.x, a0); \
                 a1 = fmaf(rlf(h1seg, 4*(c)+1), w2_##c.y, a1); \
                 a2 = fmaf(rlf(h1seg, 4*(c)+2), w2_##c.z, a2); \
                 a3 = fmaf(rlf(h1seg, 4*(c)+3), w2_##c.w, a3); }
            REP16(L2C)
#undef L2C
            h2p[(p2 << 7) | j2] = (a0 + a1) + (a2 + a3);
        }
        bar_lds();

        // ---- layer 3: reconstruct h2 in-lane (fused reduce), then logits ----
        float lg;
        {
            float h2lo = fmaxf(((h2p[lane] + h2p[128 + lane]) +
                                (h2p[256 + lane] + h2p[384 + lane])) + b2s[lane], 0.0f);
            float h2hi = fmaxf(((h2p[64 + lane] + h2p[192 + lane]) +
                                (h2p[320 + lane] + h2p[448 + lane])) + b2s[64 + lane], 0.0f);
            float lg0 = 0.0f, lg1 = 0.0f, lg2 = 0.0f, lg3 = 0.0f;
#define L3LO(c) { lg0 = fmaf(rlf(h2lo, 4*(c)+0), w3_##c.x, lg0); \
                  lg1 = fmaf(rlf(h2lo, 4*(c)+1), w3_##c.y, lg1); \
                  lg2 = fmaf(rlf(h2lo, 4*(c)+2), w3_##c.z, lg2); \
                  lg3 = fmaf(rlf(h2lo, 4*(c)+3), w3_##c.w, lg3); }
#define L3HI(c) { lg0 = fmaf(rlf(h2hi, 4*(c)-64), w3_##c.x, lg0); \
                  lg1 = fmaf(rlf(h2hi, 4*(c)-63), w3_##c.y, lg1); \
                  lg2 = fmaf(rlf(h2hi, 4*(c)-62), w3_##c.z, lg2); \
                  lg3 = fmaf(rlf(h2hi, 4*(c)-61), w3_##c.w, lg3); }
            REP16(L3LO) REP16B(L3HI)
#undef L3LO
#undef L3HI
            lg = ((lg0 + lg1) + (lg2 + lg3)) + b3r;
        }
        outL[step * 512 + t] = lg;   // fire-and-forget; lgkm barriers don't drain vmcnt

        // ---- argmax(logits + gumbel): DPP wave-max + ballot (no bpermute chain) ----
        {
            unsigned ok = orderf(lg + gv);
            unsigned m = ok;
            DPPMAXU(m, 0x111)   // row_shr:1
            DPPMAXU(m, 0x112)   // row_shr:2
            DPPMAXU(m, 0x114)   // row_shr:4
            DPPMAXU(m, 0x118)   // row_shr:8  -> lane15 of each row has row max
            DPPMAXU(m, 0x142)   // row_bcast15
            DPPMAXU(m, 0x143)   // row_bcast31 -> lane63 has wave max
            unsigned wmax = (unsigned)__builtin_amdgcn_readlane((int)m, 63);
            unsigned long long mask = __ballot(ok == wmax);
            if (lane == 0) {
                uint2 kv; kv.x = wmax; kv.y = (unsigned)(wv * 64 + (__ffsll(mask) - 1));
                kidx[wv] = kv;
            }
        }
        bar_lds();

        // ---- rotation: waves 0-3, lanes 0-15; v' = normalize(R[bi] @ v), no shuffles ----
        if (t < 256 && lane < 16) {
            uint2 K0, K1, K2, K3, K4, K5, K6, K7;
            { uint4 a = *(const uint4*)&kidx[0]; K0.x=a.x; K0.y=a.y; K1.x=a.z; K1.y=a.w; }
            { uint4 a = *(const uint4*)&kidx[2]; K2.x=a.x; K2.y=a.y; K3.x=a.z; K3.y=a.w; }
            { uint4 a = *(const uint4*)&kidx[4]; K4.x=a.x; K4.y=a.y; K5.x=a.z; K5.y=a.w; }
            { uint4 a = *(const uint4*)&kidx[6]; K6.x=a.x; K6.y=a.y; K7.x=a.z; K7.y=a.w; }
            uint2 w01 = pick2(K0, K1), w23 = pick2(K2, K3);
            uint2 w45 = pick2(K4, K5), w67 = pick2(K6, K7);
            uint2 win = pick2(pick2(w01, w23), pick2(w45, w67));
            const int bi = (int)win.y;

            const float4* rp = (const float4*)(Rtab + (size_t)bi * 256 + lane * 16);
            float4 ra = rp[0], rb = rp[1], rc = rp[2], rd = rp[3];
            float pr;
            pr = ra.x * rlf(vreg, 0);
            pr = fmaf(ra.y, rlf(vreg, 1), pr);
            pr = fmaf(ra.z, rlf(vreg, 2), pr);
            pr = fmaf(ra.w, rlf(vreg, 3), pr);
            pr = fmaf(rb.x, rlf(vreg, 4), pr);
            pr = fmaf(rb.y, rlf(vreg, 5), pr);
            pr = fmaf(rb.z, rlf(vreg, 6), pr);
            pr = fmaf(rb.w, rlf(vreg, 7), pr);
            pr = fmaf(rc.x, rlf(vreg, 8), pr);
            pr = fmaf(rc.y, rlf(vreg, 9), pr);
            pr = fmaf(rc.z, rlf(vreg, 10), pr);
            pr = fmaf(rc.w, rlf(vreg, 11), pr);
            pr = fmaf(rd.x, rlf(vreg, 12), pr);
            pr = fmaf(rd.y, rlf(vreg, 13), pr);
            pr = fmaf(rd.z, rlf(vreg, 14), pr);
            pr = fmaf(rd.w, rlf(vreg, 15), pr);

            float s2 = pr * pr;                 // sum over lanes 0-15 via DPP row-shr
            DPPADDF(s2, 0x111)
            DPPADDF(s2, 0x112)
            DPPADDF(s2, 0x114)
            DPPADDF(s2, 0x118)                  // lane15 = full row sum
            float n2 = rlf(s2, 15);
            float invn = 1.0f / sqrtf(n2);
            vreg = pr * invn;                   // lane l holds v'[l], waves 0-3 consistent
            if (step == ns - 1 && t < 16) vf_out[t] = vreg;
        }
        // no barrier here: next L1 uses only own-wave registers; h1s writes are
        // separated from this step's readers by the barriers above.
    }
}

// -------------------- K3: scores = exp(dot(v_fin, emb_row_norm)); block sums -> atomic total --------------------
extern "C" __global__ __launch_bounds__(256)
void k_scores(const float* __restrict__ emb, const float* __restrict__ vf16,
              float* __restrict__ outP, double* __restrict__ totalp)
{
    __shared__ float vfs[16];
    const int tid = threadIdx.x;
    const int bid = blockIdx.x;
    const int q = tid & 3;
    if (tid < 16) vfs[tid] = vf16[tid];
    __syncthreads();
    float v0 = vfs[q * 4 + 0], v1 = vfs[q * 4 + 1], v2 = vfs[q * 4 + 2], v3 = vfs[q * 4 + 3];

    const float4* emb4 = (const float4*)emb;
    double bsum = 0.0;
    for (long long f = (long long)bid * 256 + tid; f < (long long)M_TOTAL * 4;
         f += (long long)K3_BLOCKS * 256) {
        float4 e = emb4[f];
        long long r = f >> 2;
        float sq = fmaf(e.x, e.x, fmaf(e.y, e.y, fmaf(e.z, e.z, e.w * e.w)));
        float d  = fmaf(e.x, v0, fmaf(e.y, v1, fmaf(e.z, v2, e.w * v3)));
        sq += __shfl_xor(sq, 1);  d += __shfl_xor(d, 1);
        sq += __shfl_xor(sq, 2);  d += __shfl_xor(d, 2);
        float ex = expf(d / sqrtf(sq));   // |score| <= 1, no overflow; softmax shift cancels
        if (q == 0) {
            outP[r] = ex;
            bsum += (double)ex;
        }
    }
#pragma unroll
    for (int off = 4; off <= 32; off <<= 1) bsum += __shfl_down(bsum, off);
    __shared__ double lred[4];
    if ((tid & 63) == 0) lred[tid >> 6] = bsum;
    __syncthreads();
    if (tid == 0) atomicAdd(totalp, lred[0] + lred[1] + lred[2] + lred[3]);
}

// -------------------- K5: normalize --------------------
extern "C" __global__ __launch_bounds__(256)
void k_scale(float* __restrict__ outP, const double* __restrict__ totalp)
{
    const float inv = 1.0f / (float)totalp[0];
    long long r4 = (long long)blockIdx.x * 256 + threadIdx.x;
    if (r4 < M_TOTAL / 4) {
        float4* p = (float4*)outP;
        float4 v = p[r4];
        v.x *= inv; v.y *= inv; v.z *= inv; v.w *= inv;
        p[r4] = v;
    }
}

extern "C" void kernel_launch(void* const* d_in, const int* in_sizes, int n_in,
                              void* d_out, int out_size, void* d_ws, size_t ws_size,
                              hipStream_t stream)
{
    const float* vsrc = (const float*)d_in[0];
    const float* vtgt = (const float*)d_in[1];
    const float* emb  = (const float*)d_in[2];
    const float* tc   = (const float*)d_in[3];
    // d_in[4] = bases: structure is hard-coded (omega[i][j] = -/+ coeffs[t*, k(i,j)])
    const float* w1 = (const float*)d_in[5];
    const float* b1 = (const float*)d_in[6];
    const float* w2 = (const float*)d_in[7];
    const float* b2 = (const float*)d_in[8];
    const float* w3 = (const float*)d_in[9];
    const float* b3 = (const float*)d_in[10];
    const float* gum = (const float*)d_in[11];
    const int* nsp   = (const int*)d_in[12];

    float* outP = (float*)d_out;          // pred_marking [2M]
    float* outL = outP + M_TOTAL;         // logits [64*512]

    double* wsd      = (double*)d_ws;
    double* partials = wsd;                         // 1024*32 doubles (region sized for 2048*32)
    double* totalp   = wsd + 2048 * 32;             // 1 double
    float*  vf       = (float*)(totalp + 1);        // 16 floats

    // Scratch tables live in the pred_marking output region; fully consumed by
    // k_steps before k_scores/k_scale overwrite outP.
    float* Rtab = outP;                   // 512*256 = 131072 floats
    float* w3R  = outP + 131072;          // 512*128 =  65536 floats
    float* w2R  = outP + 196608;          // 512*64  =  32768 floats

    k_pre<<<1028, 256, 0, stream>>>(tc, Rtab, w2, w3, w2R, w3R, totalp);
    k_reduce<<<K1_BLOCKS, 256, 0, stream>>>(emb, vsrc, vtgt, partials);
    k_steps<<<1, 512, 0, stream>>>(partials, w1, b1, b2, b3, w2R, w3R, Rtab, gum, nsp, outL, vf);
    k_scores<<<K3_BLOCKS, 256, 0, stream>>>(emb, vf, outP, totalp);
    k_scale<<<(M_TOTAL / 4 + 255) / 256, 256, 0, stream>>>(outP, totalp);
}